// Round 8
// baseline (333.239 us; speedup 1.0000x reference)
//
#include <hip/hip_runtime.h>
#include <math.h>

// ---------------------------------------------------------------------------
// GraphSAGE fraud detector. CSR-gather aggregation + bf16 MFMA GEMMs.
// R24: BARRIER-FREE layer-2 GEMM (wave-private pipeline). Three structures
// (8-phase/1bl, 3buf/2bl, B-regs) all plateaued 69-70us with NO saturated
// pipe (MFMA 31/VALU 15/HBM 12%) -> the shared cost is the 32x block-wide
// gate+barrier rendezvous. New: wave-tile 64x64; each wave stages its OWN
// 64x32 A tile (3 private bufs x 4KB) via global_load_lds and self-paces
// with per-wave vmcnt(8) -- zero s_barrier in the K-loop (AITER pattern).
// FIFO invariant at gate of phase t: [B(t),A(t),B(t+1),A(t+1)] (16 ops);
// vmcnt(8) drains B(t),A(t). Body: RDA(t); MFMA(t); LDB(t+2); STGA(t+2).
// B regs double-buffered (bqA/bqB by parity, static idx). WAR on LDS buf
// (t+2)%3=(t-1)%3 safe by program order within the wave. Blocks = 4 waves,
// 48KB LDS -> 3 blocks/CU. Grid 1564 = 782 row-groups x 2 col-halves,
// m204 bijective XCD swizzle.
// R23 (kept): masked batch-of-8 gathers. R21 (kept): Wf fragment packing
// (off = ((((t*8+g)*4+nt)*4+quad)*16+cl)*8+j).
// MFMA 16x16x32 bf16: A-frag A[m=lane&15][k=quad*8+j]; C/D col=lane&15,
// row=quad*4+reg (m89/m97-verified layouts).
// ---------------------------------------------------------------------------

typedef __attribute__((ext_vector_type(8))) short bf16x8;   // 8 bf16, 4 VGPRs
typedef __attribute__((ext_vector_type(4))) float f32x4;

static inline int ceil_div(int a, int b) { return (a + b - 1) / b; }

__device__ inline float bf2f_lo(unsigned u) { return __builtin_bit_cast(float, u << 16); }
__device__ inline float bf2f_hi(unsigned u) { return __builtin_bit_cast(float, u & 0xffff0000u); }
__device__ inline unsigned f2bf(float f) {   // RNE round to bf16, bits in low 16
    unsigned u = __builtin_bit_cast(unsigned, f);
    u += 0x7fffu + ((u >> 16) & 1u);
    return u >> 16;
}

// async global->LDS, 16 B per lane; LDS dest = wave-uniform base + lane*16
#define GLOAD_LDS16(gp, lp)                                                   \
    __builtin_amdgcn_global_load_lds(                                         \
        (__attribute__((address_space(1))) void*)(gp),                        \
        (__attribute__((address_space(3))) void*)(lp), 16, 0, 0)

// ---------------- fused cvt(x,W1,W2) + deg histogram ----------------
// W2 branch packs into the Wf fragment-linear layout (see header).

__global__ void cvt3_hist_kernel(const float* __restrict__ a, unsigned short* __restrict__ ao, int na4,
                                 const float* __restrict__ b, unsigned short* __restrict__ bo, int nb4,
                                 const float* __restrict__ c, unsigned short* __restrict__ co, int nc4,
                                 const int* __restrict__ dst, int* __restrict__ deg, int E,
                                 int cvt_blocks) {
    if ((int)blockIdx.x < cvt_blocks) {
        int i = blockIdx.x * 256 + threadIdx.x;
        if (i < na4 + nb4) {
            const float* in; unsigned short* out; int k;
            if (i < na4) { in = a; out = ao; k = i; }
            else         { in = b; out = bo; k = i - na4; }
            float4 v = ((const float4*)in)[k];
            ushort4 o;
            o.x = (unsigned short)f2bf(v.x);
            o.y = (unsigned short)f2bf(v.y);
            o.z = (unsigned short)f2bf(v.z);
            o.w = (unsigned short)f2bf(v.w);
            ((ushort4*)out)[k] = o;
        } else if (i < na4 + nb4 + nc4) {
            int kk = i - na4 - nb4;            // float4 idx into W2 [512][1024]
            float4 v = ((const float4*)c)[kk];
            ushort4 o;
            o.x = (unsigned short)f2bf(v.x);
            o.y = (unsigned short)f2bf(v.y);
            o.z = (unsigned short)f2bf(v.z);
            o.w = (unsigned short)f2bf(v.w);
            const int cc = kk >> 8;            // row (col of GEMM-B), 0..511
            const int kq = kk & 255;           // float4 within row
            const int t    = kq >> 3;          // k-tile of 32
            const int quad = (kq >> 1) & 3;
            const int j0   = (kq & 1) * 4;
            const int g  = cc >> 6, nt = (cc >> 4) & 3, cl = cc & 15;
            const size_t off =
                ((((size_t)(t * 8 + g) * 4 + nt) * 4 + quad) * 16 + cl) * 8 + j0;
            *(ushort4*)(co + off) = o;
        }
    } else {
        int e = (blockIdx.x - cvt_blocks) * 256 + threadIdx.x;
        if (e < E) atomicAdd(&deg[dst[e]], 1);
    }
}

// ---------------- CSR build ----------------

// per-1024-chunk sums
__global__ __launch_bounds__(256) void chunk_reduce(const int* __restrict__ deg,
                                                    int* __restrict__ partial, int N) {
    int base = blockIdx.x * 1024;
    int s = 0;
    for (int i = threadIdx.x; i < 1024; i += 256) {
        int idx = base + i;
        if (idx < N) s += deg[idx];
    }
    #pragma unroll
    for (int off = 32; off; off >>= 1) s += __shfl_down(s, off);
    __shared__ int ws[4];
    if ((threadIdx.x & 63) == 0) ws[threadIdx.x >> 6] = s;
    __syncthreads();
    if (threadIdx.x == 0) partial[blockIdx.x] = ws[0] + ws[1] + ws[2] + ws[3];
}

// exclusive scan of P<=64 partials (one wave); writes rowstart[N]=total
__global__ void partial_scan(int* __restrict__ partial, int* __restrict__ rowstartN, int P) {
    int lane = threadIdx.x;
    int v = (lane < P) ? partial[lane] : 0;
    int incl = v;
    #pragma unroll
    for (int off = 1; off < 64; off <<= 1) {
        int t = __shfl_up(incl, off);
        if (lane >= off) incl += t;
    }
    if (lane < P) partial[lane] = incl - v;
    if (lane == 63) *rowstartN = incl;
}

// per-chunk exclusive scan + global offset; writes rowstart and cursor
__global__ __launch_bounds__(256) void chunk_scan(const int* __restrict__ deg,
                                                  const int* __restrict__ partial,
                                                  int* __restrict__ rowstart,
                                                  int* __restrict__ cursor, int N) {
    int base = blockIdx.x * 1024 + threadIdx.x * 4;
    int v[4];
    #pragma unroll
    for (int j = 0; j < 4; ++j) {
        int i = base + j;
        v[j] = (i < N) ? deg[i] : 0;
    }
    int mysum = v[0] + v[1] + v[2] + v[3];
    int incl = mysum;
    int lane = threadIdx.x & 63, wave = threadIdx.x >> 6;
    #pragma unroll
    for (int off = 1; off < 64; off <<= 1) {
        int t = __shfl_up(incl, off);
        if (lane >= off) incl += t;
    }
    __shared__ int ws[4];
    if (lane == 63) ws[wave] = incl;
    __syncthreads();
    int run = partial[blockIdx.x] + incl - mysum;
    for (int w = 0; w < wave; ++w) run += ws[w];
    #pragma unroll
    for (int j = 0; j < 4; ++j) {
        int i = base + j;
        if (i < N) { rowstart[i] = run; cursor[i] = run; }
        run += v[j];
    }
}

__global__ void bucket_kernel(const int* __restrict__ src, const int* __restrict__ dst,
                              int* __restrict__ cursor, int* __restrict__ ebuf, int E) {
    int e = blockIdx.x * 256 + threadIdx.x;
    if (e < E) {
        int pos = atomicAdd(&cursor[dst[e]], 1);
        ebuf[pos] = src[e];
    }
}

// ---------------- gather means (masked batch-of-8, R23) ----------------

// one wave per dst row; bf16 xb [N,128] -> bf16 mean [N,128]; fp32 accum.
__global__ void gather_mean_128(const int* __restrict__ rowstart, const int* __restrict__ ebuf,
                                const unsigned* __restrict__ featb, unsigned* __restrict__ outb, int N) {
    int w = (blockIdx.x * blockDim.x + threadIdx.x) >> 6;
    int lane = threadIdx.x & 63;
    if (w >= N) return;
    int e0 = rowstart[w], e1 = rowstart[w + 1];
    float ax = 0.0f, ay = 0.0f;
    for (int i = e0; i < e1; i += 8) {
        int idx[8];
        #pragma unroll
        for (int u = 0; u < 8; ++u) {
            int t = i + u;
            idx[u] = ebuf[t < e1 ? t : e1 - 1];
        }
        unsigned v[8];
        #pragma unroll
        for (int u = 0; u < 8; ++u)
            v[u] = featb[(size_t)idx[u] * 64 + lane];
        #pragma unroll
        for (int u = 0; u < 8; ++u) {
            const float s = (i + u < e1) ? 1.0f : 0.0f;
            ax += s * bf2f_lo(v[u]);
            ay += s * bf2f_hi(v[u]);
        }
    }
    float inv = 1.0f / fmaxf((float)(e1 - e0), 1.0f);
    outb[(size_t)w * 64 + lane] = f2bf(ax * inv) | (f2bf(ay * inv) << 16);
}

// one wave per dst row; bf16 feat [N,512] -> bf16 mean [N,512]; fp32 accum.
__global__ void gather_mean_512(const int* __restrict__ rowstart, const int* __restrict__ ebuf,
                                const unsigned short* __restrict__ featb,
                                unsigned short* __restrict__ outb, int N) {
    int w = (blockIdx.x * blockDim.x + threadIdx.x) >> 6;
    int lane = threadIdx.x & 63;
    if (w >= N) return;
    int e0 = rowstart[w], e1 = rowstart[w + 1];
    float a[8] = {0, 0, 0, 0, 0, 0, 0, 0};
    const uint4* base = (const uint4*)featb;     // 512 bf16/row = 64 uint4/row
    for (int i = e0; i < e1; i += 8) {
        int idx[8];
        #pragma unroll
        for (int u = 0; u < 8; ++u) {
            int t = i + u;
            idx[u] = ebuf[t < e1 ? t : e1 - 1];
        }
        uint4 v[8];
        #pragma unroll
        for (int u = 0; u < 8; ++u)
            v[u] = base[(size_t)idx[u] * 64 + lane];
        #pragma unroll
        for (int u = 0; u < 8; ++u) {
            const float s = (i + u < e1) ? 1.0f : 0.0f;
            a[0] += s * bf2f_lo(v[u].x); a[1] += s * bf2f_hi(v[u].x);
            a[2] += s * bf2f_lo(v[u].y); a[3] += s * bf2f_hi(v[u].y);
            a[4] += s * bf2f_lo(v[u].z); a[5] += s * bf2f_hi(v[u].z);
            a[6] += s * bf2f_lo(v[u].w); a[7] += s * bf2f_hi(v[u].w);
        }
    }
    float inv = 1.0f / fmaxf((float)(e1 - e0), 1.0f);
    uint4 o;
    o.x = f2bf(a[0] * inv) | (f2bf(a[1] * inv) << 16);
    o.y = f2bf(a[2] * inv) | (f2bf(a[3] * inv) << 16);
    o.z = f2bf(a[4] * inv) | (f2bf(a[5] * inv) << 16);
    o.w = f2bf(a[6] * inv) | (f2bf(a[7] * inv) << 16);
    ((uint4*)outb)[(size_t)w * 64 + lane] = o;
}

// ---------------- bf16 MFMA GEMM (R12-exact: BK=32, XCD swizzle) -----------
// Retained for layer 1 (K=256).
__global__ __launch_bounds__(256) void gemm_mfma(
    const unsigned short* __restrict__ A0,   // [N, K0] bf16
    const unsigned short* __restrict__ A1,   // [N, K1] bf16, K1 == K0
    const unsigned short* __restrict__ W,    // [C, K0+K1] bf16 row-major
    const float* __restrict__ b,             // [C] fp32
    unsigned short* __restrict__ outb,       // [N, C] bf16 (mode 0)
    const float* __restrict__ Wo,            // [C] fp32    (mode 1)
    float* __restrict__ logit,               // [N] fp32    (mode 1)
    int N, int K0, int K1, int C, int mode)
{
    // --- XCD-aware decode ---
    const int nrow = (N + 127) >> 7;
    const int id   = blockIdx.x;
    const int rowb = ((id >> 5) << 3) + (id & 7);   // rslot*8 + xcd
    const int colb = (id >> 3) & 3;
    if (rowb >= nrow) return;

    const int K = K0 + K1;
    const int S = K0;               // row stride of both A0 and A1
    __shared__ short As[2][4096];   // [128][32] per buffer, 8 KB
    __shared__ short Bs[2][4096];

    const int tid  = threadIdx.x;
    const int lane = tid & 63;
    const int wave = tid >> 6;
    const int wm = wave & 1, wn = wave >> 1;
    const int cl = lane & 15, quad = lane >> 4;
    const int row0 = rowb * 128;
    const int col0 = colb * 128;

    // staging: lane = 4r+j; wave w, load i covers tile rows w*32+i*16 .. +16
    const int r = lane >> 2;        // 0..15
    const int j = lane & 3;         // 16B chunk within the row's 64B K-slice
    const int trow0 = wave * 32 + r;
    const int trow1 = trow0 + 16;
    // clamp OOB tile rows to N-1 (loaded garbage discarded by epilogue guard)
    const int ar0 = (row0 + trow0 < N) ? row0 + trow0 : N - 1;
    const int ar1 = (row0 + trow1 < N) ? row0 + trow1 : N - 1;
    const size_t aoff0 = (size_t)ar0 * S + j * 8;
    const size_t aoff1 = (size_t)ar1 * S + j * 8;
    const size_t boff0 = (size_t)(col0 + trow0) * K + j * 8;
    const size_t boff1 = (size_t)(col0 + trow1) * K + j * 8;
    const int lds0 = (wave * 32) * 32;        // shorts; wave-uniform
    const int lds1 = (wave * 32 + 16) * 32;

    f32x4 acc[4][4];
    #pragma unroll
    for (int mt = 0; mt < 4; ++mt)
        #pragma unroll
        for (int nt = 0; nt < 4; ++nt)
            acc[mt][nt] = (f32x4){0.f, 0.f, 0.f, 0.f};

    // prologue: DMA tile 0 into buffer 0
    GLOAD_LDS16(A0 + aoff0, &As[0][lds0]);
    GLOAD_LDS16(A0 + aoff1, &As[0][lds1]);
    GLOAD_LDS16(W  + boff0, &Bs[0][lds0]);
    GLOAD_LDS16(W  + boff1, &Bs[0][lds1]);

    const int iters = K >> 5;
    for (int i = 0; i < iters; ++i) {
        const int cur = i & 1;
        // barrier drains tile i's DMA (vmcnt0) and fences tile i-1 frag reads
        __syncthreads();
        if (i + 1 < iters) {
            const int kn = (i + 1) << 5;
            const unsigned short* Ab = (kn < K0) ? (A0 + kn) : (A1 + (kn - K0));
            const unsigned short* Wb = W + kn;
            const int nb = cur ^ 1;
            GLOAD_LDS16(Ab + aoff0, &As[nb][lds0]);
            GLOAD_LDS16(Ab + aoff1, &As[nb][lds1]);
            GLOAD_LDS16(Wb + boff0, &Bs[nb][lds0]);
            GLOAD_LDS16(Wb + boff1, &Bs[nb][lds1]);
        }

        bf16x8 af[4], bfr[4];
        #pragma unroll
        for (int mt = 0; mt < 4; ++mt)
            af[mt] = *(const bf16x8*)&As[cur][(wm * 64 + mt * 16 + cl) * 32 + quad * 8];
        #pragma unroll
        for (int nt = 0; nt < 4; ++nt)
            bfr[nt] = *(const bf16x8*)&Bs[cur][(wn * 64 + nt * 16 + cl) * 32 + quad * 8];

        #pragma unroll
        for (int mt = 0; mt < 4; ++mt)
            #pragma unroll
            for (int nt = 0; nt < 4; ++nt)
                acc[mt][nt] = __builtin_amdgcn_mfma_f32_16x16x32_bf16(
                    af[mt], bfr[nt], acc[mt][nt], 0, 0, 0);
    }

    if (mode == 0) {
        #pragma unroll
        for (int nt = 0; nt < 4; ++nt) {
            const int colx = col0 + wn * 64 + nt * 16 + cl;
            const float bb = b[colx];
            #pragma unroll
            for (int mt = 0; mt < 4; ++mt) {
                #pragma unroll
                for (int rr = 0; rr < 4; ++rr) {
                    int row = row0 + wm * 64 + mt * 16 + quad * 4 + rr;
                    if (row < N)
                        outb[(size_t)row * C + colx] =
                            (unsigned short)f2bf(fmaxf(acc[mt][nt][rr] + bb, 0.0f));
                }
            }
        }
    } else {
        float bv[4], wv2[4];
        #pragma unroll
        for (int nt = 0; nt < 4; ++nt) {
            const int colx = col0 + wn * 64 + nt * 16 + cl;
            bv[nt] = b[colx];
            wv2[nt] = Wo[colx];
        }
        #pragma unroll
        for (int mt = 0; mt < 4; ++mt) {
            #pragma unroll
            for (int rr = 0; rr < 4; ++rr) {
                float s = 0.0f;
                #pragma unroll
                for (int nt = 0; nt < 4; ++nt)
                    s += fmaxf(acc[mt][nt][rr] + bv[nt], 0.0f) * wv2[nt];
                s += __shfl_xor(s, 1);
                s += __shfl_xor(s, 2);
                s += __shfl_xor(s, 4);
                s += __shfl_xor(s, 8);
                int row = row0 + wm * 64 + mt * 16 + quad * 4 + rr;
                if (cl == 0 && row < N) atomicAdd(&logit[row], s);
            }
        }
    }
}

// ---------------- layer-2: barrier-free wave-private GEMM + fused head -----
// C = relu([A0|A1] @ W^T + b); logit[row] += sum_col C[row,col]*Wo[col].
// W = Wf fragment-packed (see cvt). 256 thr = 4 independent waves; wave
// tile 64x64 (rows row0..+64, cols col0 + wc*64..+64); BK=32, 32 K-tiles.
// Per-wave: private A bufs 3 x 4KB in LDS; B double-buffered in regs.
// NO barriers in the K-loop; per-wave vmcnt(8) gate (see header proof).

#define STGA2(kt, _bf) do {                                                    \
    const unsigned short* _p = ((kt) < 16) ? (A0 + ((kt) << 5))                \
                                           : (A1 + (((kt) - 16) << 5));        \
    GLOAD_LDS16(_p + offA[0], myl + (_bf) * 4096);                             \
    GLOAD_LDS16(_p + offA[1], myl + (_bf) * 4096 + 1024);                      \
    GLOAD_LDS16(_p + offA[2], myl + (_bf) * 4096 + 2048);                      \
    GLOAD_LDS16(_p + offA[3], myl + (_bf) * 4096 + 3072);                      \
} while (0)

#define LDB2(kt, bqr) do {                                                     \
    _Pragma("unroll")                                                          \
    for (int _n = 0; _n < 4; ++_n)                                             \
        bqr[_n] = *(const bf16x8*)(W +                                         \
            (((size_t)(kt) * 8 + gB) * 4 + _n) * 512 + l * 8);                 \
} while (0)

#define RDA2(_bf) do {                                                         \
    _Pragma("unroll")                                                          \
    for (int _m = 0; _m < 4; ++_m)                                             \
        af[_m] = *(const bf16x8*)(myl + (_bf) * 4096 + aoff + _m * 1024);      \
} while (0)

#define MM16W(bqr) do {                                                        \
    _Pragma("unroll")                                                          \
    for (int _m = 0; _m < 4; ++_m)                                             \
        _Pragma("unroll")                                                      \
        for (int _n = 0; _n < 4; ++_n)                                         \
            acc[_m][_n] = __builtin_amdgcn_mfma_f32_16x16x32_bf16(             \
                af[_m], bqr[_n], acc[_m][_n], 0, 0, 0);                        \
} while (0)

#define GATE(nstr) do {                                                        \
    __builtin_amdgcn_sched_barrier(0);                                         \
    asm volatile("s_waitcnt vmcnt(" nstr ")" ::: "memory");                    \
    __builtin_amdgcn_sched_barrier(0);                                         \
} while (0)

__global__ __launch_bounds__(256, 3) void gemm2_wnb(
    const unsigned short* __restrict__ A0,   // h1b [N,512] bf16
    const unsigned short* __restrict__ A1,   // n2b [N,512] bf16
    const unsigned short* __restrict__ W,    // Wf fragment-packed [512*1024]
    const float* __restrict__ b,             // b2 [512]
    const float* __restrict__ Wo,            // [512]
    float* __restrict__ logit,               // [N]
    int N)
{
    __shared__ char lds[49152];              // 4 waves x 3 bufs x 4KB

    // bijective XCD swizzle (m204); col-halves of a row-group are
    // consecutive virt -> same XCD (A L2 reuse)
    const int nwg  = ((N + 63) >> 6) * 2;
    const int orig = blockIdx.x;
    const int xcd = orig & 7, lnum = orig >> 3;
    const int q = nwg >> 3, r = nwg & 7;
    const int virt = (xcd < r ? xcd * (q + 1) : r * (q + 1) + (xcd - r) * q) + lnum;
    const int row0 = (virt >> 1) << 6;       // 64-row tile
    const int col0 = (virt & 1) << 8;        // 256-col half

    const int tid = threadIdx.x;
    const int w = tid >> 6, l = tid & 63;    // 4 waves; wc = w
    const int cl = l & 15, quad = l >> 4;
    const int gB = (col0 >> 6) + w;          // 64-col group for B frags
    char* myl = lds + w * 12288;             // private 3 x 4KB

    // ---- A staging (inverse-swizzled global source; linear LDS dest) ----
    // instr i covers local rows i*16+(l>>2), slot l&3;
    // (row>>1)&3 = (l>>3)&3 (i*16 contributes 0 mod 4 after >>1) ->
    // logical col slot = (l&3)^((l>>3)&3); c_log elements = 8 * that.
    const int c_log = (((l & 3) ^ ((l >> 3) & 3))) * 8;
    size_t offA[4];
    #pragma unroll
    for (int i = 0; i < 4; ++i) {
        int ra = row0 + i * 16 + (l >> 2);
        if (ra > N - 1) ra = N - 1;          // clamp; epilogue guards row<N
        offA[i] = (size_t)ra * 512 + c_log;
    }

    // ---- A ds_read: phys = logical ^ (((row>>1)&3)<<4); row=mt*16+cl ->
    // (row>>1)&3 = (cl>>1)&3 (mt*8 ≡ 0 mod 4); xor bits [5:4] don't carry
    // into mt*1024.
    const int swz  = ((cl >> 1) & 3) << 4;
    const int aoff = (cl * 64 + quad * 16) ^ swz;   // + mt*1024

    f32x4 acc[4][4];
    #pragma unroll
    for (int mt = 0; mt < 4; ++mt)
        #pragma unroll
        for (int nt = 0; nt < 4; ++nt)
            acc[mt][nt] = (f32x4){0.f, 0.f, 0.f, 0.f};

    bf16x8 af[4], bqA[4], bqB[4];

    // ---- prologue: interleaved A/B so FIFO = [A0,B0,A1,B1] ----
    STGA2(0, 0); LDB2(0, bqA);
    STGA2(1, 1); LDB2(1, bqB);

    // ---- phases 0..29: gate vmcnt(8); RDA; MFMA; LDB(t+2); STGA(t+2) ----
    #pragma unroll
    for (int t = 0; t < 30; t += 2) {
        GATE("8");
        RDA2(t % 3);
        MM16W(bqA);                          // even phase
        LDB2(t + 2, bqA);
        STGA2(t + 2, (t + 2) % 3);
        GATE("8");
        RDA2((t + 1) % 3);
        MM16W(bqB);                          // odd phase
        LDB2(t + 3, bqB);
        STGA2(t + 3, (t + 3) % 3);
    }
    // phase 30 (even): queue [B30,A30,B31,A31] -> vmcnt(8) drains B30,A30
    GATE("8");
    RDA2(0);
    MM16W(bqA);
    // phase 31 (odd): queue [B31,A31] -> vmcnt(0)
    GATE("0");
    RDA2(1);
    MM16W(bqB);

    // ---- epilogue: fused ReLU + Wo dot + atomic row add (per wave) ----
    float bv[4], wv[4];
    #pragma unroll
    for (int nt = 0; nt < 4; ++nt) {
        const int colx = col0 + w * 64 + nt * 16 + cl;
        bv[nt] = b[colx];
        wv[nt] = Wo[colx];
    }
    #pragma unroll
    for (int mt = 0; mt < 4; ++mt) {
        #pragma unroll
        for (int rr = 0; rr < 4; ++rr) {
            float s = 0.0f;
            #pragma unroll
            for (int nt = 0; nt < 4; ++nt)
                s += fmaxf(acc[mt][nt][rr] + bv[nt], 0.0f) * wv[nt];
            s += __shfl_xor(s, 1);
            s += __shfl_xor(s, 2);
            s += __shfl_xor(s, 4);
            s += __shfl_xor(s, 8);
            const int row = row0 + mt * 16 + quad * 4 + rr;
            if (cl == 0 && row < N) atomicAdd(&logit[row], s);
        }
    }
}

__global__ void head_kernel(const float* __restrict__ logit, const float* __restrict__ bo,
                            float* __restrict__ out, int N) {
    int i = blockIdx.x * 256 + threadIdx.x;
    if (i < N) out[i] = 1.0f / (1.0f + expf(-(logit[i] + bo[0])));
}

extern "C" void kernel_launch(void* const* d_in, const int* in_sizes, int n_in,
                              void* d_out, int out_size, void* d_ws, size_t ws_size,
                              hipStream_t stream) {
    const float* x  = (const float*)d_in[0];
    const int*   ei = (const int*)d_in[1];
    const float* W1 = (const float*)d_in[2];
    const float* b1 = (const float*)d_in[3];
    const float* W2 = (const float*)d_in[4];
    const float* b2 = (const float*)d_in[5];
    const float* Wo = (const float*)d_in[6];
    const float* bo = (const float*)d_in[7];
    float* out = (float*)d_out;

    const int N = in_sizes[0] / 128;   // 50000
    const int E = in_sizes[1] / 2;     // 400000
    const int* src = ei;
    const int* dst = ei + E;

    char* ws = (char*)d_ws;
    size_t off = 0;
    auto alloc = [&](size_t bytes) {
        void* p = ws + off;
        off += (bytes + 255) & ~(size_t)255;
        return p;
    };
    int* deg      = (int*)alloc((size_t)N * 4);
    int* rowstart = (int*)alloc((size_t)(N + 1) * 4);
    int* cursor   = (int*)alloc((size_t)N * 4);
    int* partial  = (int*)alloc((size_t)64 * 4);
    int* ebuf     = (int*)alloc((size_t)E * 4);
    float* logit  = (float*)alloc((size_t)N * 4);
    unsigned short* xb  = (unsigned short*)alloc((size_t)N * 128 * 2);
    unsigned short* W1b = (unsigned short*)alloc((size_t)512 * 256 * 2);
    unsigned short* W2b = (unsigned short*)alloc((size_t)512 * 1024 * 2);   // Wf
    unsigned short* n1b = (unsigned short*)alloc((size_t)N * 128 * 2);
    unsigned short* h1b = (unsigned short*)alloc((size_t)N * 512 * 2);
    unsigned short* n2b = (unsigned short*)alloc((size_t)N * 512 * 2);
    (void)ws_size; (void)n_in; (void)out_size;

    hipMemsetAsync(deg,   0, (size_t)N * 4, stream);
    hipMemsetAsync(logit, 0, (size_t)N * 4, stream);

    // fused: cvt x/W1/W2(frag-pack) -> bf16  +  deg histogram
    const int na4 = N * 128 / 4, nb4 = 512 * 256 / 4, nc4 = 512 * 1024 / 4;
    const int cvt_blocks  = ceil_div(na4 + nb4 + nc4, 256);
    const int hist_blocks = ceil_div(E, 256);
    cvt3_hist_kernel<<<cvt_blocks + hist_blocks, 256, 0, stream>>>(
        x, xb, na4, W1, W1b, nb4, W2, W2b, nc4, dst, deg, E, cvt_blocks);

    // CSR build (hierarchical scan)
    const int P = ceil_div(N, 1024);   // 49
    chunk_reduce<<<P, 256, 0, stream>>>(deg, partial, N);
    partial_scan<<<1, 64, 0, stream>>>(partial, rowstart + N, P);
    chunk_scan<<<P, 256, 0, stream>>>(deg, partial, rowstart, cursor, N);
    bucket_kernel<<<ceil_div(E, 256), 256, 0, stream>>>(src, dst, cursor, ebuf, E);

    // layer 1: 128^2-tile kernel (K=256, small) — XCD-swizzled 1D grid
    const int nrow = ceil_div(N, 128);              // 391
    const int gblocks = ceil_div(nrow, 8) * 8 * 4;  // 1568
    gather_mean_128<<<ceil_div(N * 64, 256), 256, 0, stream>>>(rowstart, ebuf,
                                                               (const unsigned*)xb, (unsigned*)n1b, N);
    gemm_mfma<<<gblocks, 256, 0, stream>>>(xb, n1b, W1b, b1, h1b, nullptr, nullptr,
                                           N, 128, 128, 512, 0);

    // layer 2 + fused head: gather, then barrier-free wave-private GEMM
    gather_mean_512<<<ceil_div(N * 64, 256), 256, 0, stream>>>(rowstart, ebuf, h1b, n2b, N);
    const int g2 = ceil_div(N, 64) * 2;             // 1564 blocks
    gemm2_wnb<<<g2, 256, 0, stream>>>(h1b, n2b, W2b, b2, Wo, logit, N);

    head_kernel<<<ceil_div(N, 256), 256, 0, stream>>>(logit, bo, out, N);
}

// Round 9
// 316.407 us; speedup vs baseline: 1.0532x; 1.0532x over previous
//
#include <hip/hip_runtime.h>
#include <math.h>

// ---------------------------------------------------------------------------
// GraphSAGE fraud detector. CSR-gather aggregation + bf16 MFMA GEMMs.
// R25: (a) revert R24 barrier-free experiment (79.8us, occupancy/coalescing
// loss refuted the barrier theory). (b) Fix the REAL schedule defect in the
// R23 breg kernel: single-buffered bq gave B only ~gate+barrier to land, and
// FIFO vmcnt forced the compiler's bq-wait at MFMA(t) to drain the A(t+1)
// prefetch too (pipeline depth ~1). New schedule, 2-phase B lead with
// register double-buffer: phase t = GATE vmcnt(5); barrier; RDA(t%3);
// STGA(t+2); MFMA(t, bq[t&1]); LDB(t+2 -> bq[t&1]).
// Issue order/phase = [A(t+2), B(t+2)] -> FIFO at gate of t =
// [A(t),B(t),A(t+1),B(t+1)] = 10 ops; vmcnt(5) drains exactly A(t)+B(t);
// both get 2 full phases. bq WAR safe: MFMA(t) issues before LDB(t+2)
// overwrites bq[t&1]; phases statically unrolled (even=bqA, odd=bqB).
// (c) layer-1 ported to the same structure (gemm1_breg, KT=8, W1
// fragment-packed); old R12 gemm removed.
// R23 (kept): masked batch-of-8 gathers. Wf packing:
// off = ((((t*8+g)*4+nt)*4+quad)*16+cl)*8+j.
// MFMA 16x16x32 bf16: A-frag A[m=lane&15][k=quad*8+j]; C/D col=lane&15,
// row=quad*4+reg (m89/m97-verified layouts).
// ---------------------------------------------------------------------------

typedef __attribute__((ext_vector_type(8))) short bf16x8;   // 8 bf16, 4 VGPRs
typedef __attribute__((ext_vector_type(4))) float f32x4;

static inline int ceil_div(int a, int b) { return (a + b - 1) / b; }

__device__ inline float bf2f_lo(unsigned u) { return __builtin_bit_cast(float, u << 16); }
__device__ inline float bf2f_hi(unsigned u) { return __builtin_bit_cast(float, u & 0xffff0000u); }
__device__ inline unsigned f2bf(float f) {   // RNE round to bf16, bits in low 16
    unsigned u = __builtin_bit_cast(unsigned, f);
    u += 0x7fffu + ((u >> 16) & 1u);
    return u >> 16;
}

// async global->LDS, 16 B per lane; LDS dest = wave-uniform base + lane*16
#define GLOAD_LDS16(gp, lp)                                                   \
    __builtin_amdgcn_global_load_lds(                                         \
        (__attribute__((address_space(1))) void*)(gp),                        \
        (__attribute__((address_space(3))) void*)(lp), 16, 0, 0)

// ---------------- fused cvt(x, W1-pack, W2-pack) + deg histogram -----------
// W1 and W2 both packed into MFMA-fragment-linear layout (see header).

__global__ void cvt3_hist_kernel(const float* __restrict__ a, unsigned short* __restrict__ ao, int na4,
                                 const float* __restrict__ b, unsigned short* __restrict__ bo, int nb4,
                                 const float* __restrict__ c, unsigned short* __restrict__ co, int nc4,
                                 const int* __restrict__ dst, int* __restrict__ deg, int E,
                                 int cvt_blocks) {
    if ((int)blockIdx.x < cvt_blocks) {
        int i = blockIdx.x * 256 + threadIdx.x;
        if (i < na4) {                         // x -> xb (linear)
            float4 v = ((const float4*)a)[i];
            ushort4 o;
            o.x = (unsigned short)f2bf(v.x);
            o.y = (unsigned short)f2bf(v.y);
            o.z = (unsigned short)f2bf(v.z);
            o.w = (unsigned short)f2bf(v.w);
            ((ushort4*)ao)[i] = o;
        } else if (i < na4 + nb4) {            // W1 [512][256] -> Wf1 pack
            int kk = i - na4;
            float4 v = ((const float4*)b)[kk];
            ushort4 o;
            o.x = (unsigned short)f2bf(v.x);
            o.y = (unsigned short)f2bf(v.y);
            o.z = (unsigned short)f2bf(v.z);
            o.w = (unsigned short)f2bf(v.w);
            const int cc = kk >> 6;            // row (output col), 0..511
            const int kq = kk & 63;            // float4 within row (256 cols)
            const int t    = kq >> 3;          // k-tile of 32 (0..7)
            const int quad = (kq >> 1) & 3;
            const int j0   = (kq & 1) * 4;
            const int g  = cc >> 6, nt = (cc >> 4) & 3, cl = cc & 15;
            const size_t off =
                ((((size_t)(t * 8 + g) * 4 + nt) * 4 + quad) * 16 + cl) * 8 + j0;
            *(ushort4*)(bo + off) = o;
        } else if (i < na4 + nb4 + nc4) {      // W2 [512][1024] -> Wf2 pack
            int kk = i - na4 - nb4;
            float4 v = ((const float4*)c)[kk];
            ushort4 o;
            o.x = (unsigned short)f2bf(v.x);
            o.y = (unsigned short)f2bf(v.y);
            o.z = (unsigned short)f2bf(v.z);
            o.w = (unsigned short)f2bf(v.w);
            const int cc = kk >> 8;            // row (output col), 0..511
            const int kq = kk & 255;           // float4 within row
            const int t    = kq >> 3;          // k-tile of 32 (0..31)
            const int quad = (kq >> 1) & 3;
            const int j0   = (kq & 1) * 4;
            const int g  = cc >> 6, nt = (cc >> 4) & 3, cl = cc & 15;
            const size_t off =
                ((((size_t)(t * 8 + g) * 4 + nt) * 4 + quad) * 16 + cl) * 8 + j0;
            *(ushort4*)(co + off) = o;
        }
    } else {
        int e = (blockIdx.x - cvt_blocks) * 256 + threadIdx.x;
        if (e < E) atomicAdd(&deg[dst[e]], 1);
    }
}

// ---------------- CSR build ----------------

// per-1024-chunk sums
__global__ __launch_bounds__(256) void chunk_reduce(const int* __restrict__ deg,
                                                    int* __restrict__ partial, int N) {
    int base = blockIdx.x * 1024;
    int s = 0;
    for (int i = threadIdx.x; i < 1024; i += 256) {
        int idx = base + i;
        if (idx < N) s += deg[idx];
    }
    #pragma unroll
    for (int off = 32; off; off >>= 1) s += __shfl_down(s, off);
    __shared__ int ws[4];
    if ((threadIdx.x & 63) == 0) ws[threadIdx.x >> 6] = s;
    __syncthreads();
    if (threadIdx.x == 0) partial[blockIdx.x] = ws[0] + ws[1] + ws[2] + ws[3];
}

// exclusive scan of P<=64 partials (one wave); writes rowstart[N]=total
__global__ void partial_scan(int* __restrict__ partial, int* __restrict__ rowstartN, int P) {
    int lane = threadIdx.x;
    int v = (lane < P) ? partial[lane] : 0;
    int incl = v;
    #pragma unroll
    for (int off = 1; off < 64; off <<= 1) {
        int t = __shfl_up(incl, off);
        if (lane >= off) incl += t;
    }
    if (lane < P) partial[lane] = incl - v;
    if (lane == 63) *rowstartN = incl;
}

// per-chunk exclusive scan + global offset; writes rowstart and cursor
__global__ __launch_bounds__(256) void chunk_scan(const int* __restrict__ deg,
                                                  const int* __restrict__ partial,
                                                  int* __restrict__ rowstart,
                                                  int* __restrict__ cursor, int N) {
    int base = blockIdx.x * 1024 + threadIdx.x * 4;
    int v[4];
    #pragma unroll
    for (int j = 0; j < 4; ++j) {
        int i = base + j;
        v[j] = (i < N) ? deg[i] : 0;
    }
    int mysum = v[0] + v[1] + v[2] + v[3];
    int incl = mysum;
    int lane = threadIdx.x & 63, wave = threadIdx.x >> 6;
    #pragma unroll
    for (int off = 1; off < 64; off <<= 1) {
        int t = __shfl_up(incl, off);
        if (lane >= off) incl += t;
    }
    __shared__ int ws[4];
    if (lane == 63) ws[wave] = incl;
    __syncthreads();
    int run = partial[blockIdx.x] + incl - mysum;
    for (int w = 0; w < wave; ++w) run += ws[w];
    #pragma unroll
    for (int j = 0; j < 4; ++j) {
        int i = base + j;
        if (i < N) { rowstart[i] = run; cursor[i] = run; }
        run += v[j];
    }
}

__global__ void bucket_kernel(const int* __restrict__ src, const int* __restrict__ dst,
                              int* __restrict__ cursor, int* __restrict__ ebuf, int E) {
    int e = blockIdx.x * 256 + threadIdx.x;
    if (e < E) {
        int pos = atomicAdd(&cursor[dst[e]], 1);
        ebuf[pos] = src[e];
    }
}

// ---------------- gather means (masked batch-of-8, R23) ----------------

// one wave per dst row; bf16 xb [N,128] -> bf16 mean [N,128]; fp32 accum.
__global__ void gather_mean_128(const int* __restrict__ rowstart, const int* __restrict__ ebuf,
                                const unsigned* __restrict__ featb, unsigned* __restrict__ outb, int N) {
    int w = (blockIdx.x * blockDim.x + threadIdx.x) >> 6;
    int lane = threadIdx.x & 63;
    if (w >= N) return;
    int e0 = rowstart[w], e1 = rowstart[w + 1];
    float ax = 0.0f, ay = 0.0f;
    for (int i = e0; i < e1; i += 8) {
        int idx[8];
        #pragma unroll
        for (int u = 0; u < 8; ++u) {
            int t = i + u;
            idx[u] = ebuf[t < e1 ? t : e1 - 1];
        }
        unsigned v[8];
        #pragma unroll
        for (int u = 0; u < 8; ++u)
            v[u] = featb[(size_t)idx[u] * 64 + lane];
        #pragma unroll
        for (int u = 0; u < 8; ++u) {
            const float s = (i + u < e1) ? 1.0f : 0.0f;
            ax += s * bf2f_lo(v[u]);
            ay += s * bf2f_hi(v[u]);
        }
    }
    float inv = 1.0f / fmaxf((float)(e1 - e0), 1.0f);
    outb[(size_t)w * 64 + lane] = f2bf(ax * inv) | (f2bf(ay * inv) << 16);
}

// one wave per dst row; bf16 feat [N,512] -> bf16 mean [N,512]; fp32 accum.
__global__ void gather_mean_512(const int* __restrict__ rowstart, const int* __restrict__ ebuf,
                                const unsigned short* __restrict__ featb,
                                unsigned short* __restrict__ outb, int N) {
    int w = (blockIdx.x * blockDim.x + threadIdx.x) >> 6;
    int lane = threadIdx.x & 63;
    if (w >= N) return;
    int e0 = rowstart[w], e1 = rowstart[w + 1];
    float a[8] = {0, 0, 0, 0, 0, 0, 0, 0};
    const uint4* base = (const uint4*)featb;     // 512 bf16/row = 64 uint4/row
    for (int i = e0; i < e1; i += 8) {
        int idx[8];
        #pragma unroll
        for (int u = 0; u < 8; ++u) {
            int t = i + u;
            idx[u] = ebuf[t < e1 ? t : e1 - 1];
        }
        uint4 v[8];
        #pragma unroll
        for (int u = 0; u < 8; ++u)
            v[u] = base[(size_t)idx[u] * 64 + lane];
        #pragma unroll
        for (int u = 0; u < 8; ++u) {
            const float s = (i + u < e1) ? 1.0f : 0.0f;
            a[0] += s * bf2f_lo(v[u].x); a[1] += s * bf2f_hi(v[u].x);
            a[2] += s * bf2f_lo(v[u].y); a[3] += s * bf2f_hi(v[u].y);
            a[4] += s * bf2f_lo(v[u].z); a[5] += s * bf2f_hi(v[u].z);
            a[6] += s * bf2f_lo(v[u].w); a[7] += s * bf2f_hi(v[u].w);
        }
    }
    float inv = 1.0f / fmaxf((float)(e1 - e0), 1.0f);
    uint4 o;
    o.x = f2bf(a[0] * inv) | (f2bf(a[1] * inv) << 16);
    o.y = f2bf(a[2] * inv) | (f2bf(a[3] * inv) << 16);
    o.z = f2bf(a[4] * inv) | (f2bf(a[5] * inv) << 16);
    o.w = f2bf(a[6] * inv) | (f2bf(a[7] * inv) << 16);
    ((uint4*)outb)[(size_t)w * 64 + lane] = o;
}

// ---------------- shared breg-GEMM machinery -------------------------------
// Block 128x256, 512 thr = 8 waves (2 wr x 4 wc), wave tile 64x64, BK=32.
// LDS: A only, 3 x 8KB. B in registers from fragment-packed Wf.
// Phase t: GATE vmcnt(5); barrier; RDA(t%3); STGA(t+2); MFMA(t, bq[t&1]);
//          LDB(t+2 -> bq[t&1]).
// FIFO at gate of phase t: [A(t)1, B(t)4, A(t+1)1, B(t+1)4] = 10 ->
// vmcnt(5) drains exactly A(t)+B(t); both had 2 full phases to land.
// Compiler's bq wait at MFMA(t) is pre-satisfied (B(t) already drained) ->
// no forced drain of A(t+1). bq WAR: MFMA(t) issues before LDB(t+2)
// overwrites bq[t&1]; phases statically unrolled (even=bqA, odd=bqB).
// A-overwrite WAR: STGA(t+2) hits buf((t-1)%3); phase t-1 ds_reads retired
// before each wave's MFMA(t-1), hence before its phase-t barrier arrival.

#define STGAg(kt, SPL, STR) do {                                               \
    const unsigned short* _p = ((kt) < (SPL)) ? (A0 + ((kt) << 5))             \
                                              : (A1 + (((kt) - (SPL)) << 5));  \
    GLOAD_LDS16(_p + offA, lds + ((kt) % 3) * 8192 + w * 1024);                \
} while (0)

#define LDBg(kt, bqr) do {                                                     \
    _Pragma("unroll")                                                          \
    for (int _n = 0; _n < 4; ++_n)                                             \
        bqr[_n] = *(const bf16x8*)(W +                                         \
            (((size_t)(kt) * 8 + gB) * 4 + _n) * 512 + l * 8);                 \
} while (0)

#define RDAg(bf) do {                                                         \
    _Pragma("unroll")                                                          \
    for (int _m = 0; _m < 4; ++_m)                                             \
        af[_m] = *(const bf16x8*)(lds + (bf) * 8192 + aoff + _m * 1024);       \
} while (0)

#define MMg(bqr) do {                                                          \
    _Pragma("unroll")                                                          \
    for (int _m = 0; _m < 4; ++_m)                                             \
        _Pragma("unroll")                                                      \
        for (int _n = 0; _n < 4; ++_n)                                         \
            acc[_m][_n] = __builtin_amdgcn_mfma_f32_16x16x32_bf16(             \
                af[_m], bqr[_n], acc[_m][_n], 0, 0, 0);                        \
} while (0)

#define PHASEg(t, stg, bqr, gstr, SPL, STR) do {                               \
    __builtin_amdgcn_sched_barrier(0);                                         \
    asm volatile("s_waitcnt vmcnt(" gstr ")" ::: "memory");                    \
    __builtin_amdgcn_s_barrier();                                              \
    __builtin_amdgcn_sched_barrier(0);                                         \
    RDAg((t) % 3);                                                             \
    if (stg) STGAg((t) + 2, SPL, STR);                                         \
    __builtin_amdgcn_s_setprio(1);                                             \
    MMg(bqr);                                                                  \
    __builtin_amdgcn_s_setprio(0);                                             \
    if (stg) LDBg((t) + 2, bqr);                                               \
} while (0)

// common per-kernel prelude: decode, addresses, acc init
#define BREG_PRELUDE(STR)                                                      \
    const int nwg  = ((N + 127) >> 7) * 2;                                     \
    const int orig = blockIdx.x;                                               \
    const int xcd = orig & 7, lnum = orig >> 3;                                \
    const int q = nwg >> 3, r = nwg & 7;                                       \
    const int virt = (xcd < r ? xcd * (q + 1)                                  \
                              : r * (q + 1) + (xcd - r) * q) + lnum;           \
    const int row0 = (virt >> 1) << 7;                                         \
    const int col0 = (virt & 1) << 8;                                          \
    const int tid = threadIdx.x;                                               \
    const int w = tid >> 6, l = tid & 63;                                      \
    const int wr = w >> 2, wc = w & 3;                                         \
    const int cl = l & 15, quad = l >> 4;                                      \
    const int gB = (col0 >> 6) + wc;                                           \
    const int c_log = (((l & 3) ^ ((l >> 3) & 3))) * 8;                        \
    int ra = row0 + w * 16 + (l >> 2);                                         \
    if (ra > N - 1) ra = N - 1;                                                \
    const size_t offA = (size_t)ra * (STR) + c_log;                            \
    const int swz  = ((cl >> 1) & 3) << 4;                                     \
    const int aoff = (((wr * 64 + cl) * 64) + quad * 16) ^ swz;                \
    f32x4 acc[4][4];                                                           \
    _Pragma("unroll")                                                          \
    for (int mt = 0; mt < 4; ++mt)                                             \
        _Pragma("unroll")                                                      \
        for (int nt = 0; nt < 4; ++nt)                                         \
            acc[mt][nt] = (f32x4){0.f, 0.f, 0.f, 0.f};                         \
    bf16x8 af[4], bqA[4], bqB[4];                                              \
    (void)wr;

// ---------------- layer-1: K=256 (KT=8), mode-0 epilogue -> h1b ------------
__global__ __launch_bounds__(512, 4) void gemm1_breg(
    const unsigned short* __restrict__ A0,   // xb  [N,128] bf16
    const unsigned short* __restrict__ A1,   // n1b [N,128] bf16
    const unsigned short* __restrict__ W,    // Wf1 fragment-packed [512*256]
    const float* __restrict__ b,             // b1 [512]
    unsigned short* __restrict__ outb,       // h1b [N,512] bf16
    int N)
{
    __shared__ char lds[24576];              // A: 3 x 8KB
    BREG_PRELUDE(128)

    // prologue: FIFO = [A0,B0,A1,B1]
    STGAg(0, 4, 128); LDBg(0, bqA);
    STGAg(1, 4, 128); LDBg(1, bqB);

    #pragma unroll
    for (int t = 0; t < 6; t += 2) {
        PHASEg(t,     1, bqA, "5", 4, 128);
        PHASEg(t + 1, 1, bqB, "5", 4, 128);
    }
    PHASEg(6, 0, bqA, "5", 4, 128);
    PHASEg(7, 0, bqB, "0", 4, 128);

    // epilogue: ReLU + bias, store bf16
    #pragma unroll
    for (int nt = 0; nt < 4; ++nt) {
        const int colx = col0 + wc * 64 + nt * 16 + cl;
        const float bb = b[colx];
        #pragma unroll
        for (int mt = 0; mt < 4; ++mt) {
            #pragma unroll
            for (int rr = 0; rr < 4; ++rr) {
                const int row = row0 + wr * 64 + mt * 16 + quad * 4 + rr;
                if (row < N)
                    outb[(size_t)row * 512 + colx] =
                        (unsigned short)f2bf(fmaxf(acc[mt][nt][rr] + bb, 0.0f));
            }
        }
    }
}

// ---------------- layer-2: K=1024 (KT=32), fused head epilogue -------------
__global__ __launch_bounds__(512, 4) void gemm2_breg(
    const unsigned short* __restrict__ A0,   // h1b [N,512] bf16
    const unsigned short* __restrict__ A1,   // n2b [N,512] bf16
    const unsigned short* __restrict__ W,    // Wf2 fragment-packed [512*1024]
    const float* __restrict__ b,             // b2 [512]
    const float* __restrict__ Wo,            // [512]
    float* __restrict__ logit,               // [N]
    int N)
{
    __shared__ char lds[24576];              // A: 3 x 8KB
    BREG_PRELUDE(512)

    // prologue: FIFO = [A0,B0,A1,B1]
    STGAg(0, 16, 512); LDBg(0, bqA);
    STGAg(1, 16, 512); LDBg(1, bqB);

    #pragma unroll
    for (int t = 0; t < 30; t += 2) {
        PHASEg(t,     1, bqA, "5", 16, 512);
        PHASEg(t + 1, 1, bqB, "5", 16, 512);
    }
    PHASEg(30, 0, bqA, "5", 16, 512);
    PHASEg(31, 0, bqB, "0", 16, 512);

    // epilogue: fused ReLU + Wo dot + atomic row add
    float bv[4], wv[4];
    #pragma unroll
    for (int nt = 0; nt < 4; ++nt) {
        const int colx = col0 + wc * 64 + nt * 16 + cl;
        bv[nt] = b[colx];
        wv[nt] = Wo[colx];
    }
    #pragma unroll
    for (int mt = 0; mt < 4; ++mt) {
        #pragma unroll
        for (int rr = 0; rr < 4; ++rr) {
            float s = 0.0f;
            #pragma unroll
            for (int nt = 0; nt < 4; ++nt)
                s += fmaxf(acc[mt][nt][rr] + bv[nt], 0.0f) * wv[nt];
            s += __shfl_xor(s, 1);
            s += __shfl_xor(s, 2);
            s += __shfl_xor(s, 4);
            s += __shfl_xor(s, 8);
            const int row = row0 + wr * 64 + mt * 16 + quad * 4 + rr;
            if (cl == 0 && row < N) atomicAdd(&logit[row], s);
        }
    }
}

__global__ void head_kernel(const float* __restrict__ logit, const float* __restrict__ bo,
                            float* __restrict__ out, int N) {
    int i = blockIdx.x * 256 + threadIdx.x;
    if (i < N) out[i] = 1.0f / (1.0f + expf(-(logit[i] + bo[0])));
}

extern "C" void kernel_launch(void* const* d_in, const int* in_sizes, int n_in,
                              void* d_out, int out_size, void* d_ws, size_t ws_size,
                              hipStream_t stream) {
    const float* x  = (const float*)d_in[0];
    const int*   ei = (const int*)d_in[1];
    const float* W1 = (const float*)d_in[2];
    const float* b1 = (const float*)d_in[3];
    const float* W2 = (const float*)d_in[4];
    const float* b2 = (const float*)d_in[5];
    const float* Wo = (const float*)d_in[6];
    const float* bo = (const float*)d_in[7];
    float* out = (float*)d_out;

    const int N = in_sizes[0] / 128;   // 50000
    const int E = in_sizes[1] / 2;     // 400000
    const int* src = ei;
    const int* dst = ei + E;

    char* ws = (char*)d_ws;
    size_t off = 0;
    auto alloc = [&](size_t bytes) {
        void* p = ws + off;
        off += (bytes + 255) & ~(size_t)255;
        return p;
    };
    int* deg      = (int*)alloc((size_t)N * 4);
    int* rowstart = (int*)alloc((size_t)(N + 1) * 4);
    int* cursor   = (int*)alloc((size_t)N * 4);
    int* partial  = (int*)alloc((size_t)64 * 4);
    int* ebuf     = (int*)alloc((size_t)E * 4);
    float* logit  = (float*)alloc((size_t)N * 4);
    unsigned short* xb  = (unsigned short*)alloc((size_t)N * 128 * 2);
    unsigned short* W1b = (unsigned short*)alloc((size_t)512 * 256 * 2);    // Wf1
    unsigned short* W2b = (unsigned short*)alloc((size_t)512 * 1024 * 2);   // Wf2
    unsigned short* n1b = (unsigned short*)alloc((size_t)N * 128 * 2);
    unsigned short* h1b = (unsigned short*)alloc((size_t)N * 512 * 2);
    unsigned short* n2b = (unsigned short*)alloc((size_t)N * 512 * 2);
    (void)ws_size; (void)n_in; (void)out_size;

    hipMemsetAsync(deg,   0, (size_t)N * 4, stream);
    hipMemsetAsync(logit, 0, (size_t)N * 4, stream);

    // fused: cvt x (linear) + W1/W2 (fragment-pack) -> bf16  +  deg histogram
    const int na4 = N * 128 / 4, nb4 = 512 * 256 / 4, nc4 = 512 * 1024 / 4;
    const int cvt_blocks  = ceil_div(na4 + nb4 + nc4, 256);
    const int hist_blocks = ceil_div(E, 256);
    cvt3_hist_kernel<<<cvt_blocks + hist_blocks, 256, 0, stream>>>(
        x, xb, na4, W1, W1b, nb4, W2, W2b, nc4, dst, deg, E, cvt_blocks);

    // CSR build (hierarchical scan)
    const int P = ceil_div(N, 1024);   // 49
    chunk_reduce<<<P, 256, 0, stream>>>(deg, partial, N);
    partial_scan<<<1, 64, 0, stream>>>(partial, rowstart + N, P);
    chunk_scan<<<P, 256, 0, stream>>>(deg, partial, rowstart, cursor, N);
    bucket_kernel<<<ceil_div(E, 256), 256, 0, stream>>>(src, dst, cursor, ebuf, E);

    const int g2 = ceil_div(N, 128) * 2;            // 782 blocks

    // layer 1: gather + breg GEMM (K=256)
    gather_mean_128<<<ceil_div(N * 64, 256), 256, 0, stream>>>(rowstart, ebuf,
                                                               (const unsigned*)xb, (unsigned*)n1b, N);
    gemm1_breg<<<g2, 512, 0, stream>>>(xb, n1b, W1b, b1, h1b, N);

    // layer 2 + fused head: gather + breg GEMM (K=1024)
    gather_mean_512<<<ceil_div(N * 64, 256), 256, 0, stream>>>(rowstart, ebuf, h1b, n2b, N);
    gemm2_breg<<<g2, 512, 0, stream>>>(h1b, n2b, W2b, b2, Wo, logit, N);

    head_kernel<<<ceil_div(N, 256), 256, 0, stream>>>(logit, bo, out, N);
}

// Round 10
// 309.995 us; speedup vs baseline: 1.0750x; 1.0207x over previous
//
#include <hip/hip_runtime.h>
#include <math.h>

// ---------------------------------------------------------------------------
// GraphSAGE fraud detector. CSR-gather aggregation + bf16 MFMA GEMMs.
// R26: algorithmic restructure (5 schedule variants all plateaued 66-70us).
// Both GEMMs -> 64-row x 512-col blocks (8 waves 1x8, 64x64 wave tiles,
// full K per block): A read ONCE per row (was 2x); gemm2 epilogue owns
// complete rows -> cross-wave LDS reduce + sigmoid -> writes out[] directly
// (drops atomicAdd, logit buffer+memset, head_kernel). A staged in PAIRS of
// K-tiles (8KB = 1 global_load_lds per wave, symmetric across 8 waves) into
// 3 rotating bufs. Gates are GROUP-ALIGNED vmcnt (drain whole phase-issue
// groups; order-invariant under compiler reordering of LDB vs stage):
//   group(q) = {B(q+2) x4 [+ pair(q+4) x1 if staged]}.
//   gate(p) leaves group(p-1): KT=32: "5","5", even2-30="4", odd3-27="5",
//   29="4", 31="0"; KT=8: "5","5","4","5","4","4","4","0".
// pair(p,p+1) in group(p-4) drains at gate(p-2), barrier-published before
// first read at p. B 2-phase lead, bq double-buffered by parity (static).
// partial_scan merged into chunk_scan (one-wave re-reduce of <=64 partials).
// Launches 12 -> 9. R23 gathers kept. Wf packing kept:
// off = ((((t*8+g)*4+nt)*4+quad)*16+cl)*8+j.
// MFMA 16x16x32 bf16: A-frag A[m=lane&15][k=quad*8+j]; C/D col=lane&15,
// row=quad*4+reg (m89/m97-verified layouts).
// ---------------------------------------------------------------------------

typedef __attribute__((ext_vector_type(8))) short bf16x8;   // 8 bf16, 4 VGPRs
typedef __attribute__((ext_vector_type(4))) float f32x4;

static inline int ceil_div(int a, int b) { return (a + b - 1) / b; }

__device__ inline float bf2f_lo(unsigned u) { return __builtin_bit_cast(float, u << 16); }
__device__ inline float bf2f_hi(unsigned u) { return __builtin_bit_cast(float, u & 0xffff0000u); }
__device__ inline unsigned f2bf(float f) {   // RNE round to bf16, bits in low 16
    unsigned u = __builtin_bit_cast(unsigned, f);
    u += 0x7fffu + ((u >> 16) & 1u);
    return u >> 16;
}

// async global->LDS, 16 B per lane; LDS dest = wave-uniform base + lane*16
#define GLOAD_LDS16(gp, lp)                                                   \
    __builtin_amdgcn_global_load_lds(                                         \
        (__attribute__((address_space(1))) void*)(gp),                        \
        (__attribute__((address_space(3))) void*)(lp), 16, 0, 0)

// ---------------- fused cvt(x, W1-pack, W2-pack) + deg histogram -----------

__global__ void cvt3_hist_kernel(const float* __restrict__ a, unsigned short* __restrict__ ao, int na4,
                                 const float* __restrict__ b, unsigned short* __restrict__ bo, int nb4,
                                 const float* __restrict__ c, unsigned short* __restrict__ co, int nc4,
                                 const int* __restrict__ dst, int* __restrict__ deg, int E,
                                 int cvt_blocks) {
    if ((int)blockIdx.x < cvt_blocks) {
        int i = blockIdx.x * 256 + threadIdx.x;
        if (i < na4) {                         // x -> xb (linear)
            float4 v = ((const float4*)a)[i];
            ushort4 o;
            o.x = (unsigned short)f2bf(v.x);
            o.y = (unsigned short)f2bf(v.y);
            o.z = (unsigned short)f2bf(v.z);
            o.w = (unsigned short)f2bf(v.w);
            ((ushort4*)ao)[i] = o;
        } else if (i < na4 + nb4) {            // W1 [512][256] -> Wf1 pack
            int kk = i - na4;
            float4 v = ((const float4*)b)[kk];
            ushort4 o;
            o.x = (unsigned short)f2bf(v.x);
            o.y = (unsigned short)f2bf(v.y);
            o.z = (unsigned short)f2bf(v.z);
            o.w = (unsigned short)f2bf(v.w);
            const int cc = kk >> 6;            // row (output col), 0..511
            const int kq = kk & 63;            // float4 within row (256 cols)
            const int t    = kq >> 3;          // k-tile of 32 (0..7)
            const int quad = (kq >> 1) & 3;
            const int j0   = (kq & 1) * 4;
            const int g  = cc >> 6, nt = (cc >> 4) & 3, cl = cc & 15;
            const size_t off =
                ((((size_t)(t * 8 + g) * 4 + nt) * 4 + quad) * 16 + cl) * 8 + j0;
            *(ushort4*)(bo + off) = o;
        } else if (i < na4 + nb4 + nc4) {      // W2 [512][1024] -> Wf2 pack
            int kk = i - na4 - nb4;
            float4 v = ((const float4*)c)[kk];
            ushort4 o;
            o.x = (unsigned short)f2bf(v.x);
            o.y = (unsigned short)f2bf(v.y);
            o.z = (unsigned short)f2bf(v.z);
            o.w = (unsigned short)f2bf(v.w);
            const int cc = kk >> 8;            // row (output col), 0..511
            const int kq = kk & 255;           // float4 within row
            const int t    = kq >> 3;          // k-tile of 32 (0..31)
            const int quad = (kq >> 1) & 3;
            const int j0   = (kq & 1) * 4;
            const int g  = cc >> 6, nt = (cc >> 4) & 3, cl = cc & 15;
            const size_t off =
                ((((size_t)(t * 8 + g) * 4 + nt) * 4 + quad) * 16 + cl) * 8 + j0;
            *(ushort4*)(co + off) = o;
        }
    } else {
        int e = (blockIdx.x - cvt_blocks) * 256 + threadIdx.x;
        if (e < E) atomicAdd(&deg[dst[e]], 1);
    }
}

// ---------------- CSR build ----------------

// per-1024-chunk sums
__global__ __launch_bounds__(256) void chunk_reduce(const int* __restrict__ deg,
                                                    int* __restrict__ partial, int N) {
    int base = blockIdx.x * 1024;
    int s = 0;
    for (int i = threadIdx.x; i < 1024; i += 256) {
        int idx = base + i;
        if (idx < N) s += deg[idx];
    }
    #pragma unroll
    for (int off = 32; off; off >>= 1) s += __shfl_down(s, off);
    __shared__ int ws[4];
    if ((threadIdx.x & 63) == 0) ws[threadIdx.x >> 6] = s;
    __syncthreads();
    if (threadIdx.x == 0) partial[blockIdx.x] = ws[0] + ws[1] + ws[2] + ws[3];
}

// per-chunk exclusive scan + global offset (fused partial re-reduce, R26);
// block 0 also writes rowstart[N] = total.
__global__ __launch_bounds__(256) void chunk_scan(const int* __restrict__ deg,
                                                  const int* __restrict__ partial,
                                                  int* __restrict__ rowstart,
                                                  int* __restrict__ cursor, int N, int P) {
    __shared__ int off_sh;
    __shared__ int ws[4];
    if (threadIdx.x < 64) {
        const int j = threadIdx.x;
        const int pv = (j < P) ? partial[j] : 0;
        int tot = pv;
        #pragma unroll
        for (int o = 1; o < 64; o <<= 1) tot += __shfl_xor(tot, o);
        int mv = (j < (int)blockIdx.x) ? pv : 0;
        #pragma unroll
        for (int o = 1; o < 64; o <<= 1) mv += __shfl_xor(mv, o);
        if (j == 0) {
            off_sh = mv;
            if (blockIdx.x == 0) rowstart[N] = tot;
        }
    }
    __syncthreads();

    int base = blockIdx.x * 1024 + threadIdx.x * 4;
    int v[4];
    #pragma unroll
    for (int j = 0; j < 4; ++j) {
        int i = base + j;
        v[j] = (i < N) ? deg[i] : 0;
    }
    int mysum = v[0] + v[1] + v[2] + v[3];
    int incl = mysum;
    int lane = threadIdx.x & 63, wave = threadIdx.x >> 6;
    #pragma unroll
    for (int off = 1; off < 64; off <<= 1) {
        int t = __shfl_up(incl, off);
        if (lane >= off) incl += t;
    }
    if (lane == 63) ws[wave] = incl;
    __syncthreads();
    int run = off_sh + incl - mysum;
    for (int w = 0; w < wave; ++w) run += ws[w];
    #pragma unroll
    for (int j = 0; j < 4; ++j) {
        int i = base + j;
        if (i < N) { rowstart[i] = run; cursor[i] = run; }
        run += v[j];
    }
}

__global__ void bucket_kernel(const int* __restrict__ src, const int* __restrict__ dst,
                              int* __restrict__ cursor, int* __restrict__ ebuf, int E) {
    int e = blockIdx.x * 256 + threadIdx.x;
    if (e < E) {
        int pos = atomicAdd(&cursor[dst[e]], 1);
        ebuf[pos] = src[e];
    }
}

// ---------------- gather means (masked batch-of-8, R23) ----------------

__global__ void gather_mean_128(const int* __restrict__ rowstart, const int* __restrict__ ebuf,
                                const unsigned* __restrict__ featb, unsigned* __restrict__ outb, int N) {
    int w = (blockIdx.x * blockDim.x + threadIdx.x) >> 6;
    int lane = threadIdx.x & 63;
    if (w >= N) return;
    int e0 = rowstart[w], e1 = rowstart[w + 1];
    float ax = 0.0f, ay = 0.0f;
    for (int i = e0; i < e1; i += 8) {
        int idx[8];
        #pragma unroll
        for (int u = 0; u < 8; ++u) {
            int t = i + u;
            idx[u] = ebuf[t < e1 ? t : e1 - 1];
        }
        unsigned v[8];
        #pragma unroll
        for (int u = 0; u < 8; ++u)
            v[u] = featb[(size_t)idx[u] * 64 + lane];
        #pragma unroll
        for (int u = 0; u < 8; ++u) {
            const float s = (i + u < e1) ? 1.0f : 0.0f;
            ax += s * bf2f_lo(v[u]);
            ay += s * bf2f_hi(v[u]);
        }
    }
    float inv = 1.0f / fmaxf((float)(e1 - e0), 1.0f);
    outb[(size_t)w * 64 + lane] = f2bf(ax * inv) | (f2bf(ay * inv) << 16);
}

__global__ void gather_mean_512(const int* __restrict__ rowstart, const int* __restrict__ ebuf,
                                const unsigned short* __restrict__ featb,
                                unsigned short* __restrict__ outb, int N) {
    int w = (blockIdx.x * blockDim.x + threadIdx.x) >> 6;
    int lane = threadIdx.x & 63;
    if (w >= N) return;
    int e0 = rowstart[w], e1 = rowstart[w + 1];
    float a[8] = {0, 0, 0, 0, 0, 0, 0, 0};
    const uint4* base = (const uint4*)featb;     // 512 bf16/row = 64 uint4/row
    for (int i = e0; i < e1; i += 8) {
        int idx[8];
        #pragma unroll
        for (int u = 0; u < 8; ++u) {
            int t = i + u;
            idx[u] = ebuf[t < e1 ? t : e1 - 1];
        }
        uint4 v[8];
        #pragma unroll
        for (int u = 0; u < 8; ++u)
            v[u] = base[(size_t)idx[u] * 64 + lane];
        #pragma unroll
        for (int u = 0; u < 8; ++u) {
            const float s = (i + u < e1) ? 1.0f : 0.0f;
            a[0] += s * bf2f_lo(v[u].x); a[1] += s * bf2f_hi(v[u].x);
            a[2] += s * bf2f_lo(v[u].y); a[3] += s * bf2f_hi(v[u].y);
            a[4] += s * bf2f_lo(v[u].z); a[5] += s * bf2f_hi(v[u].z);
            a[6] += s * bf2f_lo(v[u].w); a[7] += s * bf2f_hi(v[u].w);
        }
    }
    float inv = 1.0f / fmaxf((float)(e1 - e0), 1.0f);
    uint4 o;
    o.x = f2bf(a[0] * inv) | (f2bf(a[1] * inv) << 16);
    o.y = f2bf(a[2] * inv) | (f2bf(a[3] * inv) << 16);
    o.z = f2bf(a[4] * inv) | (f2bf(a[5] * inv) << 16);
    o.w = f2bf(a[6] * inv) | (f2bf(a[7] * inv) << 16);
    ((uint4*)outb)[(size_t)w * 64 + lane] = o;
}

// ---------------- shared breg-GEMM machinery (R26: 64x512 block) -----------
// 512 thr = 8 waves 1x8; wave w owns cols w*64..+64, all 64 rows; BK=32.
// A staged in PAIRS of K-tiles (8KB: wave w writes bytes w*1024, covering
// tile kt+(w>>2), rows (w&3)*16+(l>>2), slot l&3) into 3 bufs x 8KB.
// B per wave from fragment-packed Wf (4 x 1KB dwordx4), bq double-buffered.
// Phase p: GATE(gs); barrier; RDA(p); MFMA(bq[p&1]); LDB(p+2); [STGP(p+4)].
// Group-aligned gates (see header): drain whole issue-groups, so internal
// LDB/STGP order is irrelevant to the count.

#define STGP(kt, SPL) do {                                                     \
    const int _ktw = (kt) + (w >> 2);                                          \
    const unsigned short* _p = (_ktw < (SPL))                                  \
        ? (A0 + (_ktw << 5)) : (A1 + ((_ktw - (SPL)) << 5));                   \
    GLOAD_LDS16(_p + offA, lds + (((kt) >> 1) % 3) * 8192 + w * 1024);         \
} while (0)

#define LDBg(kt, bqr) do {                                                     \
    _Pragma("unroll")                                                          \
    for (int _n = 0; _n < 4; ++_n)                                             \
        bqr[_n] = *(const bf16x8*)(W +                                         \
            (((size_t)(kt) * 8 + gB) * 4 + _n) * 512 + l * 8);                 \
} while (0)

#define RDAp(p) do {                                                           \
    _Pragma("unroll")                                                          \
    for (int _m = 0; _m < 4; ++_m)                                             \
        af[_m] = *(const bf16x8*)(lds + (((p) >> 1) % 3) * 8192 +              \
                  ((p) & 1) * 4096 + aoff + _m * 1024);                        \
} while (0)

#define MMg(bqr) do {                                                          \
    _Pragma("unroll")                                                          \
    for (int _m = 0; _m < 4; ++_m)                                             \
        _Pragma("unroll")                                                      \
        for (int _n = 0; _n < 4; ++_n)                                         \
            acc[_m][_n] = __builtin_amdgcn_mfma_f32_16x16x32_bf16(             \
                af[_m], bqr[_n], acc[_m][_n], 0, 0, 0);                        \
} while (0)

#define PH(p, bqr, gs, stg, ldb, SPL) do {                                     \
    __builtin_amdgcn_sched_barrier(0);                                         \
    asm volatile("s_waitcnt vmcnt(" gs ")" ::: "memory");                      \
    __builtin_amdgcn_s_barrier();                                              \
    __builtin_amdgcn_sched_barrier(0);                                         \
    RDAp(p);                                                                   \
    __builtin_amdgcn_s_setprio(1);                                             \
    MMg(bqr);                                                                  \
    __builtin_amdgcn_s_setprio(0);                                             \
    if (ldb) LDBg((p) + 2, bqr);                                               \
    if (stg) STGP((p) + 4, SPL);                                               \
} while (0)

// common prelude: XCD swizzle decode, addresses, acc init
#define BREG_PRELUDE(STR)                                                      \
    const int nwg  = (N + 63) >> 6;                                            \
    const int orig = blockIdx.x;                                               \
    const int xcd = orig & 7, lnum = orig >> 3;                                \
    const int q = nwg >> 3, r = nwg & 7;                                       \
    const int virt = (xcd < r ? xcd * (q + 1)                                  \
                              : r * (q + 1) + (xcd - r) * q) + lnum;           \
    const int row0 = virt << 6;                                                \
    const int tid = threadIdx.x;                                               \
    const int w = tid >> 6, l = tid & 63;                                      \
    const int cl = l & 15, quad = l >> 4;                                      \
    const int gB = w;                                                          \
    const int c_log = (((l & 3) ^ ((l >> 3) & 3))) * 8;                        \
    int ra = row0 + (w & 3) * 16 + (l >> 2);                                   \
    if (ra > N - 1) ra = N - 1;                                                \
    const size_t offA = (size_t)ra * (STR) + c_log;                            \
    const int swz  = ((cl >> 1) & 3) << 4;                                     \
    const int aoff = (cl * 64 + quad * 16) ^ swz;                              \
    f32x4 acc[4][4];                                                           \
    _Pragma("unroll")                                                          \
    for (int mt = 0; mt < 4; ++mt)                                             \
        _Pragma("unroll")                                                      \
        for (int nt = 0; nt < 4; ++nt)                                         \
            acc[mt][nt] = (f32x4){0.f, 0.f, 0.f, 0.f};                         \
    bf16x8 af[4], bqA[4], bqB[4];

// ---------------- layer-1: K=256 (KT=8) -> h1b bf16 ------------------------
__global__ __launch_bounds__(512, 4) void gemm1_breg(
    const unsigned short* __restrict__ A0,   // xb  [N,128] bf16
    const unsigned short* __restrict__ A1,   // n1b [N,128] bf16
    const unsigned short* __restrict__ W,    // Wf1 fragment-packed [512*256]
    const float* __restrict__ b,             // b1 [512]
    unsigned short* __restrict__ outb,       // h1b [N,512] bf16
    int N)
{
    __shared__ char lds[24576];              // A: 3 x 8KB (pair bufs)
    BREG_PRELUDE(128)

    // prologue groups: {pair(0,1), B(0)} , {pair(2,3), B(1)}
    STGP(0, 4); LDBg(0, bqA);
    STGP(2, 4); LDBg(1, bqB);

    PH(0, bqA, "5", 1, 1, 4);   // stage pair(4,5)
    PH(1, bqB, "5", 0, 1, 4);
    PH(2, bqA, "4", 1, 1, 4);   // stage pair(6,7)
    PH(3, bqB, "5", 0, 1, 4);
    PH(4, bqA, "4", 0, 1, 4);
    PH(5, bqB, "4", 0, 1, 4);
    PH(6, bqA, "4", 0, 0, 4);
    PH(7, bqB, "0", 0, 0, 4);

    // epilogue: ReLU + bias, store bf16 (wave-private cols)
    #pragma unroll
    for (int nt = 0; nt < 4; ++nt) {
        const int colx = w * 64 + nt * 16 + cl;
        const float bb = b[colx];
        #pragma unroll
        for (int mt = 0; mt < 4; ++mt) {
            #pragma unroll
            for (int rr = 0; rr < 4; ++rr) {
                const int row = row0 + mt * 16 + quad * 4 + rr;
                if (row < N)
                    outb[(size_t)row * 512 + colx] =
                        (unsigned short)f2bf(fmaxf(acc[mt][nt][rr] + bb, 0.0f));
            }
        }
    }
}

// ---------------- layer-2: K=1024 (KT=32), fused head -> out ---------------
__global__ __launch_bounds__(512, 4) void gemm2_breg(
    const unsigned short* __restrict__ A0,   // h1b [N,512] bf16
    const unsigned short* __restrict__ A1,   // n2b [N,512] bf16
    const unsigned short* __restrict__ W,    // Wf2 fragment-packed [512*1024]
    const float* __restrict__ b,             // b2 [512]
    const float* __restrict__ Wo,            // [512]
    const float* __restrict__ bo,            // [1]
    float* __restrict__ out,                 // [N] sigmoid output
    int N)
{
    __shared__ char lds[24576];              // A: 3 x 8KB (pair bufs)
    BREG_PRELUDE(512)

    STGP(0, 16); LDBg(0, bqA);
    STGP(2, 16); LDBg(1, bqB);

    PH(0, bqA, "5", 1, 1, 16);
    PH(1, bqB, "5", 0, 1, 16);
    #pragma unroll
    for (int p = 2; p < 28; p += 2) {
        PH(p,     bqA, "4", (p <= 26), 1, 16);
        PH(p + 1, bqB, "5", 0,         1, 16);
    }
    PH(28, bqA, "4", 0, 1, 16);
    PH(29, bqB, "4", 0, 1, 16);
    PH(30, bqA, "4", 0, 0, 16);
    PH(31, bqB, "0", 0, 0, 16);

    // epilogue: per-wave partial (ReLU + Wo dot), cross-wave LDS reduce,
    // sigmoid, direct store. ls uses bytes 0..2047 (phase-31 reads live in
    // 4096..8191 of buf0; no overlap; all waves passed barrier 31 so
    // phase-30 reads of bytes 0..4095 have retired).
    float bv[4], wv[4];
    #pragma unroll
    for (int nt = 0; nt < 4; ++nt) {
        const int colx = w * 64 + nt * 16 + cl;
        bv[nt] = b[colx];
        wv[nt] = Wo[colx];
    }
    float* ls = (float*)lds;                 // [64 rows][8 waves]
    #pragma unroll
    for (int mt = 0; mt < 4; ++mt) {
        #pragma unroll
        for (int rr = 0; rr < 4; ++rr) {
            float s = 0.0f;
            #pragma unroll
            for (int nt = 0; nt < 4; ++nt)
                s += fmaxf(acc[mt][nt][rr] + bv[nt], 0.0f) * wv[nt];
            s += __shfl_xor(s, 1);
            s += __shfl_xor(s, 2);
            s += __shfl_xor(s, 4);
            s += __shfl_xor(s, 8);
            if (cl == 0) ls[(mt * 16 + quad * 4 + rr) * 8 + w] = s;
        }
    }
    __syncthreads();
    if (tid < 64) {
        float s = 0.0f;
        #pragma unroll
        for (int w8 = 0; w8 < 8; ++w8) s += ls[tid * 8 + w8];
        const int row = row0 + tid;
        if (row < N) out[row] = 1.0f / (1.0f + expf(-(s + bo[0])));
    }
}

extern "C" void kernel_launch(void* const* d_in, const int* in_sizes, int n_in,
                              void* d_out, int out_size, void* d_ws, size_t ws_size,
                              hipStream_t stream) {
    const float* x  = (const float*)d_in[0];
    const int*   ei = (const int*)d_in[1];
    const float* W1 = (const float*)d_in[2];
    const float* b1 = (const float*)d_in[3];
    const float* W2 = (const float*)d_in[4];
    const float* b2 = (const float*)d_in[5];
    const float* Wo = (const float*)d_in[6];
    const float* bo = (const float*)d_in[7];
    float* out = (float*)d_out;

    const int N = in_sizes[0] / 128;   // 50000
    const int E = in_sizes[1] / 2;     // 400000
    const int* src = ei;
    const int* dst = ei + E;

    char* ws = (char*)d_ws;
    size_t off = 0;
    auto alloc = [&](size_t bytes) {
        void* p = ws + off;
        off += (bytes + 255) & ~(size_t)255;
        return p;
    };
    int* deg      = (int*)alloc((size_t)N * 4);
    int* rowstart = (int*)alloc((size_t)(N + 1) * 4);
    int* cursor   = (int*)alloc((size_t)N * 4);
    int* partial  = (int*)alloc((size_t)64 * 4);
    int* ebuf     = (int*)alloc((size_t)E * 4);
    unsigned short* xb  = (unsigned short*)alloc((size_t)N * 128 * 2);
    unsigned short* W1b = (unsigned short*)alloc((size_t)512 * 256 * 2);    // Wf1
    unsigned short* W2b = (unsigned short*)alloc((size_t)512 * 1024 * 2);   // Wf2
    unsigned short* n1b = (unsigned short*)alloc((size_t)N * 128 * 2);
    unsigned short* h1b = (unsigned short*)alloc((size_t)N * 512 * 2);
    unsigned short* n2b = (unsigned short*)alloc((size_t)N * 512 * 2);
    (void)ws_size; (void)n_in; (void)out_size;

    hipMemsetAsync(deg, 0, (size_t)N * 4, stream);

    // fused: cvt x (linear) + W1/W2 (fragment-pack) -> bf16  +  deg histogram
    const int na4 = N * 128 / 4, nb4 = 512 * 256 / 4, nc4 = 512 * 1024 / 4;
    const int cvt_blocks  = ceil_div(na4 + nb4 + nc4, 256);
    const int hist_blocks = ceil_div(E, 256);
    cvt3_hist_kernel<<<cvt_blocks + hist_blocks, 256, 0, stream>>>(
        x, xb, na4, W1, W1b, nb4, W2, W2b, nc4, dst, deg, E, cvt_blocks);

    // CSR build (reduce + fused scan)
    const int P = ceil_div(N, 1024);   // 49
    chunk_reduce<<<P, 256, 0, stream>>>(deg, partial, N);
    chunk_scan<<<P, 256, 0, stream>>>(deg, partial, rowstart, cursor, N, P);
    bucket_kernel<<<ceil_div(E, 256), 256, 0, stream>>>(src, dst, cursor, ebuf, E);

    const int g2 = ceil_div(N, 64);                 // 782 blocks (64-row tiles)

    // layer 1: gather + breg GEMM (K=256)
    gather_mean_128<<<ceil_div(N * 64, 256), 256, 0, stream>>>(rowstart, ebuf,
                                                               (const unsigned*)xb, (unsigned*)n1b, N);
    gemm1_breg<<<g2, 512, 0, stream>>>(xb, n1b, W1b, b1, h1b, N);

    // layer 2 + fused head: gather + breg GEMM (K=1024) -> out directly
    gather_mean_512<<<ceil_div(N * 64, 256), 256, 0, stream>>>(rowstart, ebuf, h1b, n2b, N);
    gemm2_breg<<<g2, 512, 0, stream>>>(h1b, n2b, W2b, b2, Wo, bo, out, N);
}